// Round 19
// baseline (313.324 us; speedup 1.0000x reference)
//
#include <hip/hip_runtime.h>
#include <math.h>

#define NPTS  16384
#define KNN   16
#define SEQV  8
#define NW    16
#define NBINS 512
#define BATCH 8
#define CAPM  15      // scan append words/thread (flush thr 7)

// Transposed LDS slot: row t (0..15), col (0..1023). bank = col mod 32.
#define SLOT(arr, t, col) arr[(t) * 1024 + (col)]

__device__ __forceinline__ unsigned umin_(unsigned a, unsigned b) { return a < b ? a : b; }
__device__ __forceinline__ unsigned umax_(unsigned a, unsigned b) { return a > b ? a : b; }

__device__ __forceinline__ int binOf(float x) {
    int b = (int)floorf((x + 4.0f) * 64.0f);
    return b < 0 ? 0 : (b > NBINS - 1 ? NBINS - 1 : b);
}

// merge one key into sorted ascending keys[16]
__device__ __forceinline__ void merge_one(unsigned keys[KNN], unsigned kk) {
    if (kk < keys[KNN - 1]) {
#pragma unroll
        for (int u = 0; u < KNN; ++u) {
            unsigned lo = umin_(kk, keys[u]);
            kk = umax_(kk, keys[u]);
            keys[u] = lo;
        }
    }
}

// ---------------------------------------------------------------------------
// K1: single-block counting sort by x (512 bins). 1024 threads x 16 pts.
// hist -> Hillis-Steele prefix -> scatter to sortedPc4 (x,y,z,|c|^2) + perm.
// Sentinel pad [NPTS, NPTS+256): (0,0,0,+inf) -> never accepted by filter.
// Also writes binStart[0..512] and zeroes accum.
// ---------------------------------------------------------------------------
__global__ __launch_bounds__(1024) void sort_kernel(
    const float* __restrict__ pc, float4* __restrict__ sortedPc4,
    int* __restrict__ perm, int* __restrict__ binStart,
    float* __restrict__ accum)
{
    __shared__ unsigned sA[NBINS];     // scan array
    __shared__ unsigned sCur[NBINS];   // scatter cursors

    const int tid = threadIdx.x;

    if (tid < NBINS) sA[tid] = 0u;
    __syncthreads();

#pragma unroll 1
    for (int r = 0; r < 16; ++r) {
        const int i = r * 1024 + tid;
        atomicAdd(&sA[binOf(pc[3 * i])], 1u);
    }
    __syncthreads();

    // inclusive Hillis-Steele scan over NBINS
#pragma unroll 1
    for (int off = 1; off < NBINS; off <<= 1) {
        unsigned t = (tid < NBINS && tid >= off) ? sA[tid - off] : 0u;
        __syncthreads();
        if (tid < NBINS) sA[tid] += t;
        __syncthreads();
    }

    // exclusive starts: binStart[b] = sA[b-1]; cursors likewise
    if (tid < NBINS) {
        unsigned st = (tid == 0) ? 0u : sA[tid - 1];
        binStart[tid] = (int)st;
        sCur[tid] = st;
        if (tid == NBINS - 1) binStart[NBINS] = (int)sA[NBINS - 1];
    }
    __syncthreads();

#pragma unroll 1
    for (int r = 0; r < 16; ++r) {
        const int i = r * 1024 + tid;
        float x = pc[3 * i + 0], y = pc[3 * i + 1], z = pc[3 * i + 2];
        int slot = (int)atomicAdd(&sCur[binOf(x)], 1u);
        sortedPc4[slot] = make_float4(x, y, z, fmaf(x, x, fmaf(y, y, z * z)));
        perm[slot] = i;
    }

    if (tid < 256) {   // sentinel pad: d2p = +inf -> never accepted
        sortedPc4[NPTS + tid] =
            make_float4(0.0f, 0.0f, 0.0f, __builtin_huge_valf());
    }
    if (tid == 0) {
        accum[0] = 0.0f; accum[1] = 0.0f;
        ((unsigned*)accum)[2] = 0u; ((unsigned*)accum)[3] = 0u;
    }
}

// ---------------------------------------------------------------------------
// K2: mega on sorted points. Grid 256 x 1024 (1 block/CU, 4 waves/SIMD).
// Block bx owns sorted queries [64bx, 64bx+64) (lane = query).
// T: tau0 from the 256 x-nearest sorted positions (subset -> r bound exact-
//    safe); r_i = sqrt(margined d16) -> block window [min(x-r), max(x+r)]
//    -> bin range -> contiguous candidate run [start, end).
// S: keys RESET (sample dropped -> no duplicates), R17-proven filtered scan
//    over per-wave contiguous shares (sentinel-padded), flush-tighten.
// B: transposed tree merge -> radius -> ids (sorted positions) in LDS.
// C: loss gathers via perm indirection + wsum + ticket finalize.
// key = (d2 bits & 0xFFFFC000) | sortedPos (14 bits).
// ---------------------------------------------------------------------------
__global__ __launch_bounds__(1024, 4) void mega_kernel(
    const float4* __restrict__ pc4, const int* __restrict__ perm,
    const int* __restrict__ binStart, const float* __restrict__ flow,
    const float* __restrict__ wts, float* __restrict__ accum,
    float* __restrict__ out)
{
    __shared__ unsigned uS[1024 * 16];   // 64 KB union
    float* sTau = (float*)&uS[16320];    // row15 cols 960.. (dead-zone safe)
    float* sWin = (float*)&uS[16316];    // [0]=xlo, [1]=xhi
    float* sred = (float*)&uS[15 * 1024 + 1000];

    const int tid  = threadIdx.x;
    const int lane = tid & 63;
    const int wv   = __builtin_amdgcn_readfirstlane(tid >> 6);   // 0..15
    const int i    = blockIdx.x * 64 + lane;     // sorted query position

    const float4 qv = pc4[i];
    unsigned keys[KNN];
#pragma unroll
    for (int t = 0; t < KNN; ++t) keys[t] = 0xFFFFFFFFu;

    // ================= Phase T: tau0 from 256 x-nearest ===================
    {
        int s0 = blockIdx.x * 64 - 96;
        s0 = s0 < 0 ? 0 : (s0 > NPTS - 256 ? NPTS - 256 : s0);
        const float4* cb = pc4 + s0 + wv * 16;   // wave-uniform -> s_load
        unsigned kb[16];
#pragma unroll
        for (int q = 0; q < 16; ++q) {
            const float4 c = cb[q];
            float dot = fmaf(c.x, qv.x, fmaf(c.y, qv.y, c.z * qv.z));
            float d2  = fmaxf(fmaf(-2.0f, dot, c.w) + qv.w, 0.0f);
            kb[q] = (__float_as_uint(d2) & 0xFFFFC000u)
                  | (unsigned)(s0 + wv * 16 + q);
        }
#pragma unroll
        for (int q = 0; q < 16; ++q) merge_one(keys, kb[q]);
    }
    // tree merge 16 -> 1
#pragma unroll
    for (int t = 0; t < KNN; ++t) SLOT(uS, t, tid) = keys[t];
    __syncthreads();
    if (wv < 8) {
#pragma unroll
        for (int t = 0; t < KNN; ++t) merge_one(keys, SLOT(uS, t, tid + 512));
#pragma unroll
        for (int t = 0; t < KNN; ++t) SLOT(uS, t, tid) = keys[t];
    }
    __syncthreads();
    if (wv < 4) {
#pragma unroll
        for (int t = 0; t < KNN; ++t) merge_one(keys, SLOT(uS, t, tid + 256));
#pragma unroll
        for (int t = 0; t < KNN; ++t) SLOT(uS, t, tid) = keys[t];
    }
    __syncthreads();
    if (wv < 2) {
#pragma unroll
        for (int t = 0; t < KNN; ++t) merge_one(keys, SLOT(uS, t, tid + 128));
#pragma unroll
        for (int t = 0; t < KNN; ++t) SLOT(uS, t, tid) = keys[t];
    }
    __syncthreads();
    if (wv == 0) {
#pragma unroll
        for (int t = 0; t < KNN; ++t) merge_one(keys, SLOT(uS, t, tid + 64));
        const float d16  = __uint_as_float(keys[KNN - 1] & 0xFFFFC000u);
        const float taud = fmaf(d16, 1.0002f, 1e-6f);   // margined, >= true d16
        sTau[lane] = taud - qv.w;                        // d2p-space filter bound
        const float r = sqrtf(taud);
        float xlo = qv.x - r, xhi = qv.x + r;
#pragma unroll
        for (int off = 32; off > 0; off >>= 1) {
            xlo = fminf(xlo, __shfl_down(xlo, off));
            xhi = fmaxf(xhi, __shfl_down(xhi, off));
        }
        if (lane == 0) { sWin[0] = xlo; sWin[1] = xhi; }
    }
    __syncthreads();

    // ================= Phase S: windowed filtered scan ====================
    float tauf = sTau[lane];
    {
        const int blo = __builtin_amdgcn_readfirstlane(binOf(sWin[0]));
        const int bhi = __builtin_amdgcn_readfirstlane(binOf(sWin[1]));
        const int start = binStart[blo];
        const int end   = binStart[bhi + 1];
        const int L     = end - start;
        const int wlen  = ((L + 255) >> 8) << 4;   // ceil(L/256)*16
        const int wbeg  = start + wv * wlen;       // may run into sentinel pad

#pragma unroll
        for (int t = 0; t < KNN; ++t) keys[t] = 0xFFFFFFFFu;  // drop sample
        int cnt = 0;
        unsigned* buf = &uS[tid * CAPM];           // stride 15 -> spread banks

        const float4* cb = pc4 + wbeg;             // wave-uniform -> s_load
        float4 A[BATCH], B[BATCH];
#pragma unroll
        for (int q = 0; q < BATCH; ++q) A[q] = cb[q];

        auto process = [&](const float4* C, int jbase) {
#pragma unroll
            for (int q = 0; q < BATCH; ++q) {
                const float4 c = C[q];
                float dot = fmaf(c.x, qv.x, fmaf(c.y, qv.y, c.z * qv.z));
                float d2p = fmaf(-2.0f, dot, c.w);   // inf for sentinels
                if (d2p <= tauf) {
                    float d2 = fmaxf(d2p + qv.w, 0.0f);
                    buf[cnt] = (__float_as_uint(d2) & 0xFFFFC000u)
                             | (unsigned)(wbeg + jbase + q);
                    ++cnt;
                }
            }
            if (cnt >= CAPM - BATCH) {
#pragma unroll 1
                for (int t = 0; t < cnt; ++t) merge_one(keys, buf[t]);
                cnt = 0;
                float d16n = __uint_as_float(keys[KNN - 1] & 0xFFFFC000u);
                tauf = fminf(tauf, fmaf(d16n, 1.0002f, 1e-6f) - qv.w);
            }
        };

#pragma unroll 1
        for (int jo = 0; jo < wlen; jo += 2 * BATCH) {
#pragma unroll
            for (int q = 0; q < BATCH; ++q) B[q] = cb[jo + BATCH + q];
            process(A, jo);
            if (jo + 2 * BATCH < wlen) {
#pragma unroll
                for (int q = 0; q < BATCH; ++q) A[q] = cb[jo + 2 * BATCH + q];
            }
            process(B, jo + BATCH);
        }
#pragma unroll 1
        for (int t = 0; t < cnt; ++t) merge_one(keys, buf[t]);
    }
    __syncthreads();   // scan buffers dead

    // ================= Phase B: tree merge + radius -> ids ================
#pragma unroll
    for (int t = 0; t < KNN; ++t) SLOT(uS, t, tid) = keys[t];
    __syncthreads();
    if (wv < 8) {
#pragma unroll
        for (int t = 0; t < KNN; ++t) merge_one(keys, SLOT(uS, t, tid + 512));
#pragma unroll
        for (int t = 0; t < KNN; ++t) SLOT(uS, t, tid) = keys[t];
    }
    __syncthreads();
    if (wv < 4) {
#pragma unroll
        for (int t = 0; t < KNN; ++t) merge_one(keys, SLOT(uS, t, tid + 256));
#pragma unroll
        for (int t = 0; t < KNN; ++t) SLOT(uS, t, tid) = keys[t];
    }
    __syncthreads();
    if (wv < 2) {
#pragma unroll
        for (int t = 0; t < KNN; ++t) merge_one(keys, SLOT(uS, t, tid + 128));
#pragma unroll
        for (int t = 0; t < KNN; ++t) SLOT(uS, t, tid) = keys[t];
    }
    __syncthreads();
    if (wv == 0) {
#pragma unroll
        for (int t = 0; t < KNN; ++t) merge_one(keys, SLOT(uS, t, tid + 64));
        const int id0 = (int)(keys[0] & 0x3FFFu);   // nearest (self), sorted pos
#pragma unroll
        for (int t = 0; t < KNN; ++t) {
            float d2t = __uint_as_float(keys[t] & 0xFFFFC000u);
            int   j   = (int)(keys[t] & 0x3FFFu);
            SLOT(uS, t, lane) = (unsigned)((d2t > 1.0f) ? id0 : j);
        }
    }
    __syncthreads();

    // ================= Phase C: loss + reduce + finalize ==================
    {
        const int s  = wv & 7;
        const int kh = wv >> 3;
        const int iorig = perm[i];
        const float* fs = flow + (size_t)s * NPTS * 3;
        const float fx = fs[3 * iorig + 0];
        const float fy = fs[3 * iorig + 1];
        const float fz = fs[3 * iorig + 2];

        float sum = 0.0f;
#pragma unroll
        for (int z = 0; z < 8; ++z) {
            int j = perm[(int)SLOT(uS, kh * 8 + z, lane)];
            float dx = fx - fs[3 * j + 0];
            float dy = fy - fs[3 * j + 1];
            float dz = fz - fs[3 * j + 2];
            float sq = fmaf(dx, dx, fmaf(dy, dy, dz * dz));
            sum += (sq > 0.0f) ? sqrtf(sq) : 0.0f;
        }

        float contrib = wts[iorig] * sum;
#pragma unroll
        for (int off = 32; off > 0; off >>= 1) contrib += __shfl_down(contrib, off);
        if (lane == 0) sred[wv] = contrib;

        if (wv == 0) {                       // weight sum, once per block
            float wi = wts[iorig];
#pragma unroll
            for (int off = 32; off > 0; off >>= 1) wi += __shfl_down(wi, off);
            if (lane == 0) atomicAdd(&accum[1], wi);
        }
        __syncthreads();

        if (tid == 0) {
            float c = 0.0f;
#pragma unroll
            for (int t = 0; t < NW; ++t) c += sred[t];
            atomicAdd(&accum[0], c);
            __threadfence();
            unsigned ticket = atomicAdd((unsigned*)&accum[2], 1u);
            if (ticket == gridDim.x - 1) {
                float a  = atomicAdd(&accum[0], 0.0f);
                float ws = atomicAdd(&accum[1], 0.0f);
                float v  = a / (float)(KNN * SEQV);
                out[0] = (ws > 0.0f) ? (v / ws) : v;
            }
        }
    }
}

extern "C" void kernel_launch(void* const* d_in, const int* in_sizes, int n_in,
                              void* d_out, int out_size, void* d_ws, size_t ws_size,
                              hipStream_t stream)
{
    const float* pc   = (const float*)d_in[0];   // (1, N, 3)
    const float* flow = (const float*)d_in[1];   // (SEQ, N, 3)
    const float* wts  = (const float*)d_in[2];   // (N,)
    float* out = (float*)d_out;

    // layout: accum(256B) | binStart(4*520) | perm(64KB) | sortedPc4(266KB)
    char* w = (char*)d_ws;
    float*  accum    = (float*)w;
    int*    binStart = (int*)(w + 256);
    int*    perm     = (int*)(w + 256 + 4 * 520);
    float4* spc4     = (float4*)(w + 256 + 4 * 520 + 4 * NPTS + 1792); // 16B-align pad

    sort_kernel<<<1, 1024, 0, stream>>>(pc, spc4, perm, binStart, accum);
    mega_kernel<<<NPTS / 64, 1024, 0, stream>>>(spc4, perm, binStart,
                                                flow, wts, accum, out);
}